// Round 3
// baseline (8234.176 us; speedup 1.0000x reference)
//
#include <hip/hip_runtime.h>

typedef _Float16 f16;
typedef _Float16 f16x4 __attribute__((ext_vector_type(4)));
typedef _Float16 f16x8 __attribute__((ext_vector_type(8)));
typedef float    f32x4 __attribute__((ext_vector_type(4)));

#define MFMA16(a, b, c) __builtin_amdgcn_mfma_f32_16x16x32_f16(a, b, c, 0, 0, 0)

// Problem constants
static constexpr int kS  = 512;
static constexpr int kB  = 64;
static constexpr int kDI = 512;
static constexpr int kDL = 1024;
static constexpr int kV  = 50257;

// Geometry: 4 independent groups x 16 batch rows; 16 blocks per group, each
// block owns 64 h-columns (4 waves x 16-col tile, full K per wave -> no
// cross-wave reduction). 64 blocks total, 1 block/CU (LDS-bound).
static constexpr int NGRP = 4;
static constexpr int GSZ  = 16;
static constexpr int NBLK = NGRP * GSZ;

union U128 { unsigned long long q[2]; f16x8 v; };

// ---------------------------------------------------------------------------
// LLC-coherent exchange primitives — byte-for-byte the R1-proven protocol.
// Stores: write-through to LLC (sc0 sc1, untracked by compiler but counted in
// HW vmcnt). Loads: agent-scope relaxed atomics (sc1 path, bypass stale
// L1/L2, LLC-served, fully compiler-tracked => parallel issue, no asm hazards).
static __device__ __forceinline__ void store_llc_f16(f16* p, f16 v) {
  unsigned v32 = (unsigned)__builtin_bit_cast(unsigned short, v);
  asm volatile("global_store_short %0, %1, off sc0 sc1" :: "v"(p), "v"(v32) : "memory");
}

// Poll this group's 16 flags (one 64B line) with one coalesced wave load.
static __device__ __forceinline__ void wait_phase(const unsigned* flg, unsigned goal, int lane) {
  const unsigned* p = flg + (lane & 15);
  for (;;) {
    unsigned f = __hip_atomic_load(p, __ATOMIC_RELAXED, __HIP_MEMORY_SCOPE_AGENT);
    if (__all((int)(f >= goal))) return;
    __builtin_amdgcn_s_sleep(1);
  }
}

// Per-wave store drain -> block-wide join -> publish this block's phase seq.
// vmcnt(0) retires ALL this block's loads+stores (incl. the asm sc-stores and
// the plain H stores) before the flag is issued, so flag-visibility implies
// data-visibility for the sc1 readers.
static __device__ __forceinline__ void drain_signal(unsigned* myflag, int tid, unsigned seq) {
  asm volatile("s_waitcnt vmcnt(0)" ::: "memory");
  __syncthreads();
  if (tid == 0)
    asm volatile("global_store_dword %0, %1, off sc0 sc1" :: "v"(myflag), "v"(seq) : "memory");
}

// ---------------------------------------------------------------------------
// K0a: emb fp32 -> f16
__global__ void k_emb_convert(const float* __restrict__ src, f16* __restrict__ dst, int n4) {
  int i = blockIdx.x * 256 + threadIdx.x;
  if (i >= n4) return;
  float4 v = ((const float4*)src)[i];
  f16x4 o = {(f16)v.x, (f16)v.y, (f16)v.z, (f16)v.w};
  ((f16x4*)dst)[i] = o;
}

// K0b: pack bottom (x_emb) halves of W_z|W_r|W_h into B-fragment order (k_xproj).
__global__ void k_pack_bot(const float* __restrict__ Wz, const float* __restrict__ Wr,
                           const float* __restrict__ Wh, f16* __restrict__ Bpk) {
  int tid = blockIdx.x * 256 + threadIdx.x;  // 196608
  int lane = tid & 63, kstep = (tid >> 6) & 15, ntile = tid >> 10;
  int n = ntile * 16 + (lane & 15);
  const float* W = (n < 1024) ? Wz : (n < 2048 ? Wr : Wh);
  int ncol = n & 1023;
  int kbase = kstep * 32 + (lane >> 4) * 8;
  f16x8 v;
#pragma unroll
  for (int j = 0; j < 8; ++j) v[j] = (f16)W[(size_t)(1024 + kbase + j) * 1024 + ncol];
  ((f16x8*)Bpk)[tid] = v;
}

// K0c: pack top (h) halves into B-fragment order:
// Tpk[m(3)][tile(64)][kstep(32)][lane(64)][j(8)]  (col = tile*16 + lane&15)
__global__ void k_pack_top(const float* __restrict__ Wz, const float* __restrict__ Wr,
                           const float* __restrict__ Wh, f16* __restrict__ Tpk) {
  int tid = blockIdx.x * 256 + threadIdx.x;  // 393216
  int lane = tid & 63, kstep = (tid >> 6) & 31, wg = (tid >> 11) & 63, m = tid >> 17;
  const float* W = (m == 0) ? Wz : (m == 1 ? Wr : Wh);
  int col = wg * 16 + (lane & 15);
  int kbase = kstep * 32 + (lane >> 4) * 8;
  f16x8 v;
#pragma unroll
  for (int j = 0; j < 8; ++j) v[j] = (f16)W[(size_t)(kbase + j) * 1024 + col];
  ((f16x8*)Tpk)[tid] = v;
}

// K0d: h0 fp32 -> f16 in the per-group fragment-split exchange layout.
// 8B word i = g*4096 + ks*128 + plane*64 + lane; slots j(0..3):
//   h[g*16 + (lane&15)][ks*32 + (lane>>4)*8 + plane*4 + j]
__global__ void k_h_convert(const float* __restrict__ h0, f16* __restrict__ hfrag) {
  int i = blockIdx.x * 256 + threadIdx.x;   // 16384 words
  int lane = i & 63, plane = (i >> 6) & 1, ks = (i >> 7) & 31, g = i >> 12;
  int row = g * 16 + (lane & 15);
  int k = ks * 32 + (lane >> 4) * 8 + plane * 4;
  f16x4 v;
#pragma unroll
  for (int j = 0; j < 4; ++j) v[j] = (f16)h0[(size_t)row * kDL + k + j];
  ((f16x4*)hfrag)[i] = v;
}

// ---------------------------------------------------------------------------
// K1: X-projection GEMM with fused embedding gather (unchanged, proven).
__global__ __launch_bounds__(256, 2)
void k_xproj(const int* __restrict__ X, const f16* __restrict__ emb16,
             const f16* __restrict__ Bpk, f16* Xzr, f16* __restrict__ Xh) {
  const int bm = blockIdx.x / 24, bn = blockIdx.x % 24;
  const int tid = threadIdx.x;
  const int w = tid >> 6, lane = tid & 63, l15 = lane & 15, quad = lane >> 4;

  __shared__ int tok[128];
  __shared__ f16x8 Asm[8 * 2 * 64];
  __shared__ f16x8 Bsm[8 * 2 * 64];

  if (tid < 128) tok[tid] = X[bm * 128 + tid];
  __syncthreads();

  f32x4 zero4 = {0.f, 0.f, 0.f, 0.f};
  f32x4 acc[4][4];
#pragma unroll
  for (int i = 0; i < 4; ++i)
#pragma unroll
    for (int j = 0; j < 4; ++j) acc[i][j] = zero4;

  const int mtb = (w & 1) * 4, ntb = (w >> 1) * 4;

  for (int ki = 0; ki < 8; ++ki) {
#pragma unroll
    for (int c = 0; c < 4; ++c) {
      int cid = c * 256 + tid;
      int r = cid >> 3, kc = cid & 7;
      Asm[((r >> 4) * 2 + (kc >> 2)) * 64 + (kc & 3) * 16 + (r & 15)] =
          *(const f16x8*)(emb16 + (size_t)tok[r] * kDI + ki * 64 + kc * 8);
    }
#pragma unroll
    for (int c = 0; c < 4; ++c) {
      int cid = c * 256 + tid;
      int nt = cid >> 7, ks = (cid >> 6) & 1, ln = cid & 63;
      Bsm[cid] = ((const f16x8*)Bpk)[((size_t)(bn * 8 + nt) * 16 + (ki * 2 + ks)) * 64 + ln];
    }
    __syncthreads();
#pragma unroll
    for (int ks = 0; ks < 2; ++ks) {
      f16x8 a[4], b[4];
#pragma unroll
      for (int i = 0; i < 4; ++i) a[i] = Asm[((mtb + i) * 2 + ks) * 64 + lane];
#pragma unroll
      for (int j = 0; j < 4; ++j) b[j] = Bsm[((ntb + j) * 2 + ks) * 64 + lane];
#pragma unroll
      for (int i = 0; i < 4; ++i)
#pragma unroll
        for (int j = 0; j < 4; ++j) acc[i][j] = MFMA16(a[i], b[j], acc[i][j]);
    }
    __syncthreads();
  }

  const int rowb = bm * 128 + (w & 1) * 64;
  const int colb = bn * 128 + (w >> 1) * 64;
#pragma unroll
  for (int i = 0; i < 4; ++i)
#pragma unroll
    for (int j = 0; j < 4; ++j)
#pragma unroll
      for (int reg = 0; reg < 4; ++reg) {
        int row = rowb + i * 16 + quad * 4 + reg;
        int col = colb + j * 16 + l15;
        f16 v = (f16)acc[i][j][reg];
        if (col < 2048) Xzr[(size_t)row * 2048 + col] = v;
        else            Xh[(size_t)row * 1024 + (col - 2048)] = v;
      }
}

// ---------------------------------------------------------------------------
// K2: persistent GRU. Block (g, blk): group g owns batch rows [16g,16g+16);
// block owns cols [64*blk, 64*blk+64); wave w owns 16-col tile (blk*4+w) over
// FULL K. Wz/Wr fragments in VGPRs, Wh in 128 KiB LDS. 2 group-internal
// 16-wide flag barriers per step; no intra-block reduction.
__global__ __launch_bounds__(256, 1)
void k_gru(const float* __restrict__ h0, const f16* __restrict__ Tpk,
           const f16* Xzr /* aliases H */, const f16* __restrict__ Xh,
           f16* hfrag, f16* rhfrag, unsigned* sync, float* H) {
  __shared__ f16x8 ldsWh[4 * 32 * 64];   // [wave-tile][ks][lane] = 128 KiB

  const int g = blockIdx.x >> 4, blk = blockIdx.x & 15;
  const int tid = threadIdx.x;
  const int w = tid >> 6, lane = tid & 63, l15 = lane & 15, quad = lane >> 4;

  const f16x8* T = (const f16x8*)Tpk;
  const int tile = blk * 4 + w;          // global 16-col tile of this wave
  const int c    = tile * 16 + l15;      // this lane's output column

  // Wz/Wr fragments for full K (32 each -> 256 VGPRs, loop-invariant)
  f16x8 wz[32], wr[32];
#pragma unroll
  for (int s = 0; s < 32; ++s) {
    wz[s] = T[((size_t)(0 * 64 + tile) * 32 + s) * 64 + lane];
    wr[s] = T[((size_t)(1 * 64 + tile) * 32 + s) * 64 + lane];
  }
  // Wh col-tiles [4*blk, 4*blk+4) -> LDS (contiguous copy)
#pragma unroll 4
  for (int it = 0; it < 32; ++it) {
    int idx = it * 256 + tid;
    ldsWh[idx] = T[(size_t)(128 + blk * 4 + (idx >> 11)) * 2048 + (idx & 2047)];
  }
  __syncthreads();

  const int rowb = g * 16;

  // Persistent fp32 state: lane owns rows quad*4+r4 (r4=0..3) of column c
  // (exactly the MFMA 16x16 C/D layout: col = lane&15, row = quad*4 + reg).
  float hreg[4], zreg[4];
#pragma unroll
  for (int r4 = 0; r4 < 4; ++r4)
    hreg[r4] = h0[(size_t)(rowb + quad * 4 + r4) * kDL + c];

  // Scatter address of value h[row][c] in the fragment-split layout:
  //   ks = c>>5, k' = c&31, qp = k'>>3, plane = (k'>>2)&1, slot = k'&3,
  //   lane_dst = qp*16 + row_local  (row_local = quad*4 + r4; +1 lane_dst/r4
  //   => +4 f16 per r4)
  const int ks_s  = tile >> 1;                    // = c>>5 (uniform per wave)
  const int qp    = (w & 1) * 2 + (l15 >> 3);
  const int plane = (l15 >> 2) & 1;
  const size_t scat =
      (((size_t)g * 4096) + ((size_t)ks_s * 2 + plane) * 64 + qp * 16 + quad * 4) * 4 + (l15 & 3);
  f16* const rh_p = rhfrag + scat;
  f16* const h_p  = hfrag + scat;

  // Exchange read bases: fragment s = words [s*128 + lane] (plane0) and +64.
  const unsigned long long* hq = (const unsigned long long*)hfrag + (size_t)g * 4096 + lane;
  const unsigned long long* rq = (const unsigned long long*)rhfrag + (size_t)g * 4096 + lane;

  unsigned* flg = sync + g * 32;   // group's 16 flags (own 128B line)
  unsigned seq = 0;

#pragma unroll 1
  for (int t = 0; t < kS; ++t) {
    // prefetch x-projections (independent; fly during the flag wait)
    float xz[4], xr[4], xh[4];
#pragma unroll
    for (int r4 = 0; r4 < 4; ++r4) {
      size_t row = (size_t)t * kB + rowb + quad * 4 + r4;
      xz[r4] = (float)Xzr[row * 2048 + c];
      xr[r4] = (float)Xzr[row * 2048 + 1024 + c];
      xh[r4] = (float)Xh[row * 1024 + c];
    }

    // ---------- phase A: z,r (full K) ----------
    wait_phase(flg, seq, lane);          // h(t-1) published by all 16 (seq==2t)

    f16x8 af[32];
#pragma unroll
    for (int s = 0; s < 32; ++s) {
      U128 u;
      u.q[0] = __hip_atomic_load(hq + s * 128,      __ATOMIC_RELAXED, __HIP_MEMORY_SCOPE_AGENT);
      u.q[1] = __hip_atomic_load(hq + s * 128 + 64, __ATOMIC_RELAXED, __HIP_MEMORY_SCOPE_AGENT);
      af[s] = u.v;
    }

    f32x4 az0 = {0.f,0.f,0.f,0.f}, az1 = {0.f,0.f,0.f,0.f};
    f32x4 ar0 = {0.f,0.f,0.f,0.f}, ar1 = {0.f,0.f,0.f,0.f};
#pragma unroll
    for (int s = 0; s < 32; s += 2) {
      az0 = MFMA16(af[s],     wz[s],     az0);
      ar0 = MFMA16(af[s],     wr[s],     ar0);
      az1 = MFMA16(af[s + 1], wz[s + 1], az1);
      ar1 = MFMA16(af[s + 1], wr[s + 1], ar1);
    }
    f32x4 zsum = az0 + az1, rsum = ar0 + ar1;

#pragma unroll
    for (int r4 = 0; r4 < 4; ++r4) {
      float zin = zsum[r4] + xz[r4];
      float rin = rsum[r4] + xr[r4];
      float z = 1.f / (1.f + __expf(-zin));
      float r = 1.f / (1.f + __expf(-rin));
      zreg[r4] = z;
      store_llc_f16(rh_p + r4 * 4, (f16)(r * hreg[r4]));
    }
    drain_signal(flg + blk, tid, ++seq);   // publish r*h (seq==2t+1)

    // ---------- phase B: candidate + state update ----------
    wait_phase(flg, seq, lane);            // r*h published by all 16

    f16x8 bf[32];
#pragma unroll
    for (int s = 0; s < 32; ++s) {
      U128 u;
      u.q[0] = __hip_atomic_load(rq + s * 128,      __ATOMIC_RELAXED, __HIP_MEMORY_SCOPE_AGENT);
      u.q[1] = __hip_atomic_load(rq + s * 128 + 64, __ATOMIC_RELAXED, __HIP_MEMORY_SCOPE_AGENT);
      bf[s] = u.v;
    }

    f32x4 ac0 = {0.f,0.f,0.f,0.f}, ac1 = {0.f,0.f,0.f,0.f};
#pragma unroll
    for (int s = 0; s < 32; s += 2) {
      ac0 = MFMA16(bf[s],     ldsWh[(w * 32 + s) * 64 + lane],     ac0);
      ac1 = MFMA16(bf[s + 1], ldsWh[(w * 32 + s + 1) * 64 + lane], ac1);
    }
    f32x4 csum = ac0 + ac1;

#pragma unroll
    for (int r4 = 0; r4 < 4; ++r4) {
      float cin = csum[r4] + xh[r4];
      float cand = 1.f - 2.f / (__expf(2.f * cin) + 1.f);  // tanh
      float hn = hreg[r4] + zreg[r4] * (cand - hreg[r4]);
      hreg[r4] = hn;
      H[((size_t)t * kB + rowb + quad * 4 + r4) * kDL + c] = hn;  // fp32 output
      store_llc_f16(h_p + r4 * 4, (f16)hn);                       // f16 broadcast
    }
    drain_signal(flg + blk, tid, ++seq);   // publish h(t) (seq==2t+2)
  }
}

// ---------------------------------------------------------------------------
extern "C" void kernel_launch(void* const* d_in, const int* in_sizes, int n_in,
                              void* d_out, int out_size, void* d_ws, size_t ws_size,
                              hipStream_t stream) {
  const int*   X   = (const int*)d_in[0];
  const float* h0  = (const float*)d_in[1];
  const float* emb = (const float*)d_in[2];
  const float* Wz  = (const float*)d_in[3];
  const float* Wr  = (const float*)d_in[4];
  const float* Wh  = (const float*)d_in[5];
  float* H = (float*)d_out;

  char* ws = (char*)d_ws;
  size_t o = 0;
  f16* emb16 = (f16*)(ws + o); o += (size_t)kV * kDI * 2;          // 51,463,168
  f16* Bpk   = (f16*)(ws + o); o += (size_t)3072 * 512 * 2;        //  3,145,728
  f16* Tpk   = (f16*)(ws + o); o += (size_t)3 * 1024 * 1024 * 2;   //  6,291,456
  f16* hfrag = (f16*)(ws + o); o += (size_t)NGRP * 4096 * 8;       //    131,072
  f16* rhfrag= (f16*)(ws + o); o += (size_t)NGRP * 4096 * 8;       //    131,072
  unsigned* sync = (unsigned*)(ws + o); o += 1024;                 // 4 groups x 128B
  f16* Xh    = (f16*)(ws + o); o += (size_t)kS * kB * kDL * 2;     // 67,108,864
  // total ~128.3 MB of d_ws; z/r projections (f16, 134.2 MB) live inside d_out.
  f16* Xzr = (f16*)d_out;

  hipMemsetAsync(sync, 0, 1024, stream);

  int n4 = kV * kDI / 4;
  k_emb_convert<<<(n4 + 255) / 256, 256, 0, stream>>>(emb, emb16, n4);
  k_pack_bot<<<196608 / 256, 256, 0, stream>>>(Wz, Wr, Wh, Bpk);
  k_pack_top<<<393216 / 256, 256, 0, stream>>>(Wz, Wr, Wh, Tpk);
  k_h_convert<<<64, 256, 0, stream>>>(h0, hfrag);
  k_xproj<<<256 * 24, 256, 0, stream>>>(X, emb16, Bpk, Xzr, Xh);
  k_gru<<<NBLK, 256, 0, stream>>>(h0, Tpk, Xzr, Xh, hfrag, rhfrag, sync, H);
}

// Round 4
// 7147.816 us; speedup vs baseline: 1.1520x; 1.1520x over previous
//
#include <hip/hip_runtime.h>

typedef _Float16 f16;
typedef _Float16 f16x4 __attribute__((ext_vector_type(4)));
typedef _Float16 f16x8 __attribute__((ext_vector_type(8)));
typedef float    f32x4 __attribute__((ext_vector_type(4)));

#define MFMA16(a, b, c) __builtin_amdgcn_mfma_f32_16x16x32_f16(a, b, c, 0, 0, 0)

// Problem constants
static constexpr int kS  = 512;
static constexpr int kB  = 64;
static constexpr int kDI = 512;
static constexpr int kDL = 1024;
static constexpr int kV  = 50257;

// Geometry: 4 independent groups x 16 batch rows. Each group: 64 blocks, one
// 16-col tile each (full 1024 cols), wave w = K-quarter (R1's proven light
// structure: 96 weight VGPRs, depth-8 chains, LDS cross-wave reduce).
// 256 blocks total = all 256 CUs.
static constexpr int NGRP = 4;
static constexpr int GSZ  = 64;   // blocks per group (barrier width, R1-proven)
static constexpr int NBLK = NGRP * GSZ;

union U128 { unsigned long long q[2]; f16x8 v; };

// ---------------------------------------------------------------------------
// LLC-coherent exchange primitives — byte-for-byte the R1-proven protocol.
static __device__ __forceinline__ void store_llc_f16(f16* p, f16 v) {
  unsigned v32 = (unsigned)__builtin_bit_cast(unsigned short, v);
  asm volatile("global_store_short %0, %1, off sc0 sc1" :: "v"(p), "v"(v32) : "memory");
}

// Poll this group's 64 flags (4 lines) with one coalesced wave load.
static __device__ __forceinline__ void wait_phase(const unsigned* flg, unsigned goal, int lane) {
  const unsigned* p = flg + lane;
  for (;;) {
    unsigned f = __hip_atomic_load(p, __ATOMIC_RELAXED, __HIP_MEMORY_SCOPE_AGENT);
    if (__all((int)(f >= goal))) return;
    __builtin_amdgcn_s_sleep(1);
  }
}

// Per-wave store drain -> block-wide join -> publish this block's phase seq.
static __device__ __forceinline__ void drain_signal(unsigned* myflag, int tid, unsigned seq) {
  asm volatile("s_waitcnt vmcnt(0)" ::: "memory");
  __syncthreads();
  if (tid == 0)
    asm volatile("global_store_dword %0, %1, off sc0 sc1" :: "v"(myflag), "v"(seq) : "memory");
}

// ---------------------------------------------------------------------------
// K0a: emb fp32 -> f16
__global__ void k_emb_convert(const float* __restrict__ src, f16* __restrict__ dst, int n4) {
  int i = blockIdx.x * 256 + threadIdx.x;
  if (i >= n4) return;
  float4 v = ((const float4*)src)[i];
  f16x4 o = {(f16)v.x, (f16)v.y, (f16)v.z, (f16)v.w};
  ((f16x4*)dst)[i] = o;
}

// K0b: pack bottom (x_emb) halves of W_z|W_r|W_h into B-fragment order (k_xproj).
__global__ void k_pack_bot(const float* __restrict__ Wz, const float* __restrict__ Wr,
                           const float* __restrict__ Wh, f16* __restrict__ Bpk) {
  int tid = blockIdx.x * 256 + threadIdx.x;  // 196608
  int lane = tid & 63, kstep = (tid >> 6) & 15, ntile = tid >> 10;
  int n = ntile * 16 + (lane & 15);
  const float* W = (n < 1024) ? Wz : (n < 2048 ? Wr : Wh);
  int ncol = n & 1023;
  int kbase = kstep * 32 + (lane >> 4) * 8;
  f16x8 v;
#pragma unroll
  for (int j = 0; j < 8; ++j) v[j] = (f16)W[(size_t)(1024 + kbase + j) * 1024 + ncol];
  ((f16x8*)Bpk)[tid] = v;
}

// K0c: pack top (h) halves into B-fragment order:
// Tpk[m(3)][tile(64)][kstep(32)][lane(64)][j(8)]  (col = tile*16 + lane&15)
__global__ void k_pack_top(const float* __restrict__ Wz, const float* __restrict__ Wr,
                           const float* __restrict__ Wh, f16* __restrict__ Tpk) {
  int tid = blockIdx.x * 256 + threadIdx.x;  // 393216
  int lane = tid & 63, kstep = (tid >> 6) & 31, wg = (tid >> 11) & 63, m = tid >> 17;
  const float* W = (m == 0) ? Wz : (m == 1 ? Wr : Wh);
  int col = wg * 16 + (lane & 15);
  int kbase = kstep * 32 + (lane >> 4) * 8;
  f16x8 v;
#pragma unroll
  for (int j = 0; j < 8; ++j) v[j] = (f16)W[(size_t)(kbase + j) * 1024 + col];
  ((f16x8*)Tpk)[tid] = v;
}

// K0d: h0 fp32 -> f16 in the per-group fragment-split exchange layout.
// 8B word i = g*4096 + ks*128 + plane*64 + lane; slots j(0..3):
//   h[g*16 + (lane&15)][ks*32 + (lane>>4)*8 + plane*4 + j]
// (identical to R3's proven layout)
__global__ void k_h_convert(const float* __restrict__ h0, f16* __restrict__ hfrag) {
  int i = blockIdx.x * 256 + threadIdx.x;   // 16384 words
  int lane = i & 63, plane = (i >> 6) & 1, ks = (i >> 7) & 31, g = i >> 12;
  int row = g * 16 + (lane & 15);
  int k = ks * 32 + (lane >> 4) * 8 + plane * 4;
  f16x4 v;
#pragma unroll
  for (int j = 0; j < 4; ++j) v[j] = (f16)h0[(size_t)row * kDL + k + j];
  ((f16x4*)hfrag)[i] = v;
}

// ---------------------------------------------------------------------------
// K1: X-projection GEMM with fused embedding gather (unchanged, proven).
__global__ __launch_bounds__(256, 2)
void k_xproj(const int* __restrict__ X, const f16* __restrict__ emb16,
             const f16* __restrict__ Bpk, f16* Xzr, f16* __restrict__ Xh) {
  const int bm = blockIdx.x / 24, bn = blockIdx.x % 24;
  const int tid = threadIdx.x;
  const int w = tid >> 6, lane = tid & 63, l15 = lane & 15, quad = lane >> 4;

  __shared__ int tok[128];
  __shared__ f16x8 Asm[8 * 2 * 64];
  __shared__ f16x8 Bsm[8 * 2 * 64];

  if (tid < 128) tok[tid] = X[bm * 128 + tid];
  __syncthreads();

  f32x4 zero4 = {0.f, 0.f, 0.f, 0.f};
  f32x4 acc[4][4];
#pragma unroll
  for (int i = 0; i < 4; ++i)
#pragma unroll
    for (int j = 0; j < 4; ++j) acc[i][j] = zero4;

  const int mtb = (w & 1) * 4, ntb = (w >> 1) * 4;

  for (int ki = 0; ki < 8; ++ki) {
#pragma unroll
    for (int c = 0; c < 4; ++c) {
      int cid = c * 256 + tid;
      int r = cid >> 3, kc = cid & 7;
      Asm[((r >> 4) * 2 + (kc >> 2)) * 64 + (kc & 3) * 16 + (r & 15)] =
          *(const f16x8*)(emb16 + (size_t)tok[r] * kDI + ki * 64 + kc * 8);
    }
#pragma unroll
    for (int c = 0; c < 4; ++c) {
      int cid = c * 256 + tid;
      int nt = cid >> 7, ks = (cid >> 6) & 1, ln = cid & 63;
      Bsm[cid] = ((const f16x8*)Bpk)[((size_t)(bn * 8 + nt) * 16 + (ki * 2 + ks)) * 64 + ln];
    }
    __syncthreads();
#pragma unroll
    for (int ks = 0; ks < 2; ++ks) {
      f16x8 a[4], b[4];
#pragma unroll
      for (int i = 0; i < 4; ++i) a[i] = Asm[((mtb + i) * 2 + ks) * 64 + lane];
#pragma unroll
      for (int j = 0; j < 4; ++j) b[j] = Bsm[((ntb + j) * 2 + ks) * 64 + lane];
#pragma unroll
      for (int i = 0; i < 4; ++i)
#pragma unroll
        for (int j = 0; j < 4; ++j) acc[i][j] = MFMA16(a[i], b[j], acc[i][j]);
    }
    __syncthreads();
  }

  const int rowb = bm * 128 + (w & 1) * 64;
  const int colb = bn * 128 + (w >> 1) * 64;
#pragma unroll
  for (int i = 0; i < 4; ++i)
#pragma unroll
    for (int j = 0; j < 4; ++j)
#pragma unroll
      for (int reg = 0; reg < 4; ++reg) {
        int row = rowb + i * 16 + quad * 4 + reg;
        int col = colb + j * 16 + l15;
        f16 v = (f16)acc[i][j][reg];
        if (col < 2048) Xzr[(size_t)row * 2048 + col] = v;
        else            Xh[(size_t)row * 1024 + (col - 2048)] = v;
      }
}

// ---------------------------------------------------------------------------
// K2: persistent GRU. Block (g, blk): group g owns rows [16g,16g+16); block
// owns cols [16*blk, 16*blk+16); wave w owns K-quarter [256w, 256w+256).
// Per wave per phase: 16 exchange loads + 16 (A) / 8 (B) MFMAs + LDS reduce.
// Wave 0 holds h-state, applies activations, does all exchange/H stores.
__global__ __launch_bounds__(256, 1)
void k_gru(const float* __restrict__ h0, const f16* __restrict__ Tpk,
           const f16* Xzr /* aliases H */, const f16* __restrict__ Xh,
           f16* hfrag, f16* rhfrag, unsigned* sync, float* H) {
  __shared__ f32x4 red[4][2][64];   // [src wave][z|r][lane] = 8 KiB

  const int g = blockIdx.x >> 6, blk = blockIdx.x & 63;
  const int tid = threadIdx.x;
  const int w = tid >> 6, lane = tid & 63, l15 = lane & 15, quad = lane >> 4;

  const f16x8* T = (const f16x8*)Tpk;

  // Per-wave K-quarter weights (96 VGPRs, loop-invariant — R1 budget)
  f16x8 wz[8], wr[8], wh[8];
#pragma unroll
  for (int s = 0; s < 8; ++s) {
    wz[s] = T[((size_t)(0 * 64 + blk) * 32 + w * 8 + s) * 64 + lane];
    wr[s] = T[((size_t)(1 * 64 + blk) * 32 + w * 8 + s) * 64 + lane];
    wh[s] = T[((size_t)(2 * 64 + blk) * 32 + w * 8 + s) * 64 + lane];
  }

  const int rowb = g * 16;
  const int c = blk * 16 + l15;   // this lane's output column (wave 0 roles)

  // Persistent fp32 state (wave 0 only): rows quad*4+r4 of column c
  // (MFMA 16x16 C/D layout: col = lane&15, row = quad*4 + reg).
  float hreg[4], zreg[4];
#pragma unroll
  for (int r4 = 0; r4 < 4; ++r4)
    hreg[r4] = h0[(size_t)(rowb + quad * 4 + r4) * kDL + c];

  // Scatter address of h[row][c] in the fragment-split layout (wave 0):
  //   ks = c>>5 = blk>>1, k' = c&31 = (blk&1)*16 + l15,
  //   qp = (blk&1)*2 + (l15>>3), plane = (l15>>2)&1, slot = l15&3,
  //   lane_dst = qp*16 + quad*4 + r4  (+1 lane_dst per r4 => +4 f16)
  const size_t scat =
      (((size_t)g * 4096) + ((size_t)(blk >> 1) * 2 + ((l15 >> 2) & 1)) * 64 +
       ((blk & 1) * 2 + (l15 >> 3)) * 16 + quad * 4) * 4 + (l15 & 3);
  f16* const rh_p = rhfrag + scat;
  f16* const h_p  = hfrag + scat;

  // Exchange read bases: wave w reads frags s = w*8..w*8+8 (two planes each).
  const unsigned long long* hq =
      (const unsigned long long*)hfrag + (size_t)g * 4096 + (size_t)w * 8 * 128 + lane;
  const unsigned long long* rq =
      (const unsigned long long*)rhfrag + (size_t)g * 4096 + (size_t)w * 8 * 128 + lane;

  unsigned* flg = sync + g * 64;   // group's 64 flags (4 lines)
  unsigned seq = 0;

#pragma unroll 1
  for (int t = 0; t < kS; ++t) {
    // prefetch x-projections (wave 0 only; fly during the flag wait)
    float xz[4], xr[4], xh[4];
    if (w == 0) {
#pragma unroll
      for (int r4 = 0; r4 < 4; ++r4) {
        size_t row = (size_t)t * kB + rowb + quad * 4 + r4;
        xz[r4] = (float)Xzr[row * 2048 + c];
        xr[r4] = (float)Xzr[row * 2048 + 1024 + c];
        xh[r4] = (float)Xh[row * 1024 + c];
      }
    }

    // ---------- phase A: z,r partials over this wave's K-quarter ----------
    wait_phase(flg, seq, lane);          // h(t-1) published by all 64 (seq==2t)

    f16x8 af[8];
#pragma unroll
    for (int s = 0; s < 8; ++s) {
      U128 u;
      u.q[0] = __hip_atomic_load(hq + s * 128,      __ATOMIC_RELAXED, __HIP_MEMORY_SCOPE_AGENT);
      u.q[1] = __hip_atomic_load(hq + s * 128 + 64, __ATOMIC_RELAXED, __HIP_MEMORY_SCOPE_AGENT);
      af[s] = u.v;
    }

    f32x4 az = {0.f,0.f,0.f,0.f}, ar = {0.f,0.f,0.f,0.f};
#pragma unroll
    for (int s = 0; s < 8; ++s) {
      az = MFMA16(af[s], wz[s], az);
      ar = MFMA16(af[s], wr[s], ar);
    }
    red[w][0][lane] = az;
    red[w][1][lane] = ar;
    __syncthreads();

    if (w == 0) {
      f32x4 zs = red[0][0][lane] + red[1][0][lane] + red[2][0][lane] + red[3][0][lane];
      f32x4 rs = red[0][1][lane] + red[1][1][lane] + red[2][1][lane] + red[3][1][lane];
#pragma unroll
      for (int r4 = 0; r4 < 4; ++r4) {
        float zin = zs[r4] + xz[r4];
        float rin = rs[r4] + xr[r4];
        float z = 1.f / (1.f + __expf(-zin));
        float r = 1.f / (1.f + __expf(-rin));
        zreg[r4] = z;
        store_llc_f16(rh_p + r4 * 4, (f16)(r * hreg[r4]));
      }
    }
    drain_signal(flg + blk, tid, ++seq);   // publish r*h (seq==2t+1)

    // ---------- phase B: candidate + state update ----------
    wait_phase(flg, seq, lane);            // r*h published by all 64

    f16x8 bf[8];
#pragma unroll
    for (int s = 0; s < 8; ++s) {
      U128 u;
      u.q[0] = __hip_atomic_load(rq + s * 128,      __ATOMIC_RELAXED, __HIP_MEMORY_SCOPE_AGENT);
      u.q[1] = __hip_atomic_load(rq + s * 128 + 64, __ATOMIC_RELAXED, __HIP_MEMORY_SCOPE_AGENT);
      bf[s] = u.v;
    }

    f32x4 ac = {0.f,0.f,0.f,0.f};
#pragma unroll
    for (int s = 0; s < 8; ++s)
      ac = MFMA16(bf[s], wh[s], ac);
    red[w][0][lane] = ac;
    __syncthreads();

    if (w == 0) {
      f32x4 cs = red[0][0][lane] + red[1][0][lane] + red[2][0][lane] + red[3][0][lane];
#pragma unroll
      for (int r4 = 0; r4 < 4; ++r4) {
        float cin = cs[r4] + xh[r4];
        float cand = 1.f - 2.f / (__expf(2.f * cin) + 1.f);  // tanh
        float hn = hreg[r4] + zreg[r4] * (cand - hreg[r4]);
        hreg[r4] = hn;
        H[((size_t)t * kB + rowb + quad * 4 + r4) * kDL + c] = hn;  // fp32 output
        store_llc_f16(h_p + r4 * 4, (f16)hn);                       // f16 broadcast
      }
    }
    drain_signal(flg + blk, tid, ++seq);   // publish h(t) (seq==2t+2)
  }
}

// ---------------------------------------------------------------------------
extern "C" void kernel_launch(void* const* d_in, const int* in_sizes, int n_in,
                              void* d_out, int out_size, void* d_ws, size_t ws_size,
                              hipStream_t stream) {
  const int*   X   = (const int*)d_in[0];
  const float* h0  = (const float*)d_in[1];
  const float* emb = (const float*)d_in[2];
  const float* Wz  = (const float*)d_in[3];
  const float* Wr  = (const float*)d_in[4];
  const float* Wh  = (const float*)d_in[5];
  float* H = (float*)d_out;

  char* ws = (char*)d_ws;
  size_t o = 0;
  f16* emb16 = (f16*)(ws + o); o += (size_t)kV * kDI * 2;          // 51,463,168
  f16* Bpk   = (f16*)(ws + o); o += (size_t)3072 * 512 * 2;        //  3,145,728
  f16* Tpk   = (f16*)(ws + o); o += (size_t)3 * 1024 * 1024 * 2;   //  6,291,456
  f16* hfrag = (f16*)(ws + o); o += (size_t)NGRP * 4096 * 8;       //    131,072
  f16* rhfrag= (f16*)(ws + o); o += (size_t)NGRP * 4096 * 8;       //    131,072
  unsigned* sync = (unsigned*)(ws + o); o += 1024;                 // 4 groups x 64 flags
  f16* Xh    = (f16*)(ws + o); o += (size_t)kS * kB * kDL * 2;     // 67,108,864
  // total ~128.3 MB of d_ws; z/r projections (f16, 134.2 MB) live inside d_out.
  f16* Xzr = (f16*)d_out;

  hipMemsetAsync(sync, 0, 1024, stream);

  int n4 = kV * kDI / 4;
  k_emb_convert<<<(n4 + 255) / 256, 256, 0, stream>>>(emb, emb16, n4);
  k_pack_bot<<<196608 / 256, 256, 0, stream>>>(Wz, Wr, Wh, Bpk);
  k_pack_top<<<393216 / 256, 256, 0, stream>>>(Wz, Wr, Wh, Tpk);
  k_h_convert<<<64, 256, 0, stream>>>(h0, hfrag);
  k_xproj<<<256 * 24, 256, 0, stream>>>(X, emb16, Bpk, Xzr, Xh);
  k_gru<<<NBLK, 256, 0, stream>>>(h0, Tpk, Xzr, Xh, hfrag, rhfrag, sync, H);
}